// Round 5
// baseline (1301.161 us; speedup 1.0000x reference)
//
#include <hip/hip_runtime.h>
#include <math.h>

// HashGridEncoder: L=16 levels, T=2^19 entries, F=2 features, N=1M points.
// Thread = one point; fully unrolled level loop; 8 random float2 gathers/level.

static constexpr unsigned T_SZ  = 524288u;      // 2^19
static constexpr unsigned TMASK = T_SZ - 1u;
static constexpr int      LVLS  = 16;
static constexpr unsigned PI1   = 2654435761u;
static constexpr unsigned PI2   = 805459861u;

typedef float vfloat4 __attribute__((ext_vector_type(4)));  // native vec for nontemporal store

struct HGParams {
  float cell[LVLS];   // (float)(2.0 / res) — matches JAX weak-type f32 demotion
  float inv[LVLS];    // 1.0f / cell
};

__global__ __launch_bounds__(256) void hg_encode(
    const float* __restrict__ xyz,
    const float* __restrict__ tables,
    float* __restrict__ out,
    int n, HGParams P) {
  int p = blockIdx.x * 256 + threadIdx.x;
  if (p >= n) return;

  const float x = xyz[3 * (size_t)p + 0];
  const float y = xyz[3 * (size_t)p + 1];
  const float z = xyz[3 * (size_t)p + 2];

  float o[2 * LVLS];

#pragma unroll
  for (int l = 0; l < LVLS; ++l) {
    const float cell = P.cell[l];
    const float inv  = P.inv[l];

    // min_index = floor((xyz - BB_MIN)/cell); BB_MIN = -1
    const float fx = floorf((x + 1.0f) * inv);
    const float fy = floorf((y + 1.0f) * inv);
    const float fz = floorf((z + 1.0f) * inv);
    // d = (xyz - (min_index*cell + BB_MIN)) / cell, all f32 like reference
    const float dx = (x - (fx * cell - 1.0f)) * inv;
    const float dy = (y - (fy * cell - 1.0f)) * inv;
    const float dz = (z - (fz * cell - 1.0f)) * inv;

    // hash components; corner+1 folds into +PI (uint wraparound matches ref)
    const unsigned hx0 = (unsigned)(int)fx;           // * PI0 = 1
    const unsigned hy0 = (unsigned)(int)fy * PI1;
    const unsigned hz0 = (unsigned)(int)fz * PI2;
    const unsigned hx1 = hx0 + 1u;
    const unsigned hy1 = hy0 + PI1;
    const unsigned hz1 = hz0 + PI2;

    const unsigned i000 = (hx0 ^ hy0 ^ hz0) & TMASK;
    const unsigned i001 = (hx0 ^ hy0 ^ hz1) & TMASK;
    const unsigned i010 = (hx0 ^ hy1 ^ hz0) & TMASK;
    const unsigned i011 = (hx0 ^ hy1 ^ hz1) & TMASK;
    const unsigned i100 = (hx1 ^ hy0 ^ hz0) & TMASK;
    const unsigned i101 = (hx1 ^ hy0 ^ hz1) & TMASK;
    const unsigned i110 = (hx1 ^ hy1 ^ hz0) & TMASK;
    const unsigned i111 = (hx1 ^ hy1 ^ hz1) & TMASK;

    const float2* __restrict__ tb = (const float2*)tables + (size_t)l * T_SZ;
    const float2 e000 = tb[i000];
    const float2 e001 = tb[i001];
    const float2 e010 = tb[i010];
    const float2 e011 = tb[i011];
    const float2 e100 = tb[i100];
    const float2 e101 = tb[i101];
    const float2 e110 = tb[i110];
    const float2 e111 = tb[i111];

    // trilinear weights, product order (x*y)*z like reference prod over axis
    const float ax = 1.0f - dx, ay = 1.0f - dy, az = 1.0f - dz;
    const float w00 = ax * ay, w01 = ax * dy, w10 = dx * ay, w11 = dx * dy;
    const float w000 = w00 * az, w001 = w00 * dz;
    const float w010 = w01 * az, w011 = w01 * dz;
    const float w100 = w10 * az, w101 = w10 * dz;
    const float w110 = w11 * az, w111 = w11 * dz;

    float s0 = w000 * e000.x;
    float s1 = w000 * e000.y;
    s0 = fmaf(w001, e001.x, s0); s1 = fmaf(w001, e001.y, s1);
    s0 = fmaf(w010, e010.x, s0); s1 = fmaf(w010, e010.y, s1);
    s0 = fmaf(w011, e011.x, s0); s1 = fmaf(w011, e011.y, s1);
    s0 = fmaf(w100, e100.x, s0); s1 = fmaf(w100, e100.y, s1);
    s0 = fmaf(w101, e101.x, s0); s1 = fmaf(w101, e101.y, s1);
    s0 = fmaf(w110, e110.x, s0); s1 = fmaf(w110, e110.y, s1);
    s0 = fmaf(w111, e111.x, s0); s1 = fmaf(w111, e111.y, s1);

    o[2 * l + 0] = s0;
    o[2 * l + 1] = s1;
  }

  // 128B per point; nontemporal so the 128MB stream doesn't evict table lines
  vfloat4* o4 = (vfloat4*)(out + (size_t)p * (2 * LVLS));
#pragma unroll
  for (int i = 0; i < 8; ++i) {
    vfloat4 v = { o[4 * i + 0], o[4 * i + 1], o[4 * i + 2], o[4 * i + 3] };
    __builtin_nontemporal_store(v, &o4[i]);
  }
}

extern "C" void kernel_launch(void* const* d_in, const int* in_sizes, int n_in,
                              void* d_out, int out_size, void* d_ws, size_t ws_size,
                              hipStream_t stream) {
  const float* xyz    = (const float*)d_in[0];
  const float* tables = (const float*)d_in[1];
  float* out = (float*)d_out;
  const int n = in_sizes[0] / 3;

  // Replicate Python's RES computation bit-for-bit (same glibc libm doubles).
  HGParams P;
  const double B = exp((log(2048.0) - log(16.0)) / 15.0);
  for (int i = 0; i < LVLS; ++i) {
    const int r = (int)floor(16.0 * pow(B, (double)i));
    const double cd = 2.0 / (double)r;
    P.cell[i] = (float)cd;
    P.inv[i]  = 1.0f / P.cell[i];
  }

  const int blocks = (n + 255) / 256;
  hg_encode<<<blocks, 256, 0, stream>>>(xyz, tables, out, n, P);
}

// Round 6
// 645.961 us; speedup vs baseline: 2.0143x; 2.0143x over previous
//
#include <hip/hip_runtime.h>
#include <math.h>

// HashGridEncoder, level-major restructure.
// Pass 1 (hg_gather): grid ordered so all resident blocks share one level ->
//   its 4 MiB table fits each XCD's L2 exactly; random gathers become L2 hits.
//   Output written coalesced to level-major scratch [L][N] float2 in d_ws.
// Pass 2 (hg_transpose): LDS-tiled transpose scratch -> out [N][2L].
// Fallback (hg_encode): point-major single kernel if ws_size too small.

static constexpr unsigned T_SZ  = 524288u;      // 2^19
static constexpr unsigned TMASK = T_SZ - 1u;
static constexpr int      LVLS  = 16;
static constexpr unsigned PI1   = 2654435761u;
static constexpr unsigned PI2   = 805459861u;

struct HGParams {
  float cell[LVLS];   // (float)(2.0 / res)
  float inv[LVLS];    // 1.0f / cell
};

__device__ __forceinline__ void encode_one_level(
    float x, float y, float z, float cell, float inv,
    const float2* __restrict__ tb, float& s0, float& s1) {
  const float fx = floorf((x + 1.0f) * inv);
  const float fy = floorf((y + 1.0f) * inv);
  const float fz = floorf((z + 1.0f) * inv);
  const float dx = (x - (fx * cell - 1.0f)) * inv;
  const float dy = (y - (fy * cell - 1.0f)) * inv;
  const float dz = (z - (fz * cell - 1.0f)) * inv;

  const unsigned hx0 = (unsigned)(int)fx;           // * PI0 = 1
  const unsigned hy0 = (unsigned)(int)fy * PI1;
  const unsigned hz0 = (unsigned)(int)fz * PI2;
  const unsigned hx1 = hx0 + 1u;
  const unsigned hy1 = hy0 + PI1;
  const unsigned hz1 = hz0 + PI2;

  const unsigned i000 = (hx0 ^ hy0 ^ hz0) & TMASK;
  const unsigned i001 = (hx0 ^ hy0 ^ hz1) & TMASK;
  const unsigned i010 = (hx0 ^ hy1 ^ hz0) & TMASK;
  const unsigned i011 = (hx0 ^ hy1 ^ hz1) & TMASK;
  const unsigned i100 = (hx1 ^ hy0 ^ hz0) & TMASK;
  const unsigned i101 = (hx1 ^ hy0 ^ hz1) & TMASK;
  const unsigned i110 = (hx1 ^ hy1 ^ hz0) & TMASK;
  const unsigned i111 = (hx1 ^ hy1 ^ hz1) & TMASK;

  const float2 e000 = tb[i000];
  const float2 e001 = tb[i001];
  const float2 e010 = tb[i010];
  const float2 e011 = tb[i011];
  const float2 e100 = tb[i100];
  const float2 e101 = tb[i101];
  const float2 e110 = tb[i110];
  const float2 e111 = tb[i111];

  const float ax = 1.0f - dx, ay = 1.0f - dy, az = 1.0f - dz;
  const float w00 = ax * ay, w01 = ax * dy, w10 = dx * ay, w11 = dx * dy;
  const float w000 = w00 * az, w001 = w00 * dz;
  const float w010 = w01 * az, w011 = w01 * dz;
  const float w100 = w10 * az, w101 = w10 * dz;
  const float w110 = w11 * az, w111 = w11 * dz;

  s0 = w000 * e000.x;
  s1 = w000 * e000.y;
  s0 = fmaf(w001, e001.x, s0); s1 = fmaf(w001, e001.y, s1);
  s0 = fmaf(w010, e010.x, s0); s1 = fmaf(w010, e010.y, s1);
  s0 = fmaf(w011, e011.x, s0); s1 = fmaf(w011, e011.y, s1);
  s0 = fmaf(w100, e100.x, s0); s1 = fmaf(w100, e100.y, s1);
  s0 = fmaf(w101, e101.x, s0); s1 = fmaf(w101, e101.y, s1);
  s0 = fmaf(w110, e110.x, s0); s1 = fmaf(w110, e110.y, s1);
  s0 = fmaf(w111, e111.x, s0); s1 = fmaf(w111, e111.y, s1);
}

// ---------------- Pass 1: level-major gather -> scratch [L][N] float2 -------
__global__ __launch_bounds__(256) void hg_gather(
    const float* __restrict__ xyz,
    const float* __restrict__ tables,
    float2* __restrict__ scratch,
    int n, int nb, HGParams P) {
  const int lvl = blockIdx.x / nb;               // consecutive blocks share a level
  const int p   = (blockIdx.x % nb) * 256 + threadIdx.x;
  if (p >= n) return;

  const float x = xyz[3 * (size_t)p + 0];
  const float y = xyz[3 * (size_t)p + 1];
  const float z = xyz[3 * (size_t)p + 2];

  const float2* __restrict__ tb = (const float2*)tables + (size_t)lvl * T_SZ;
  float s0, s1;
  encode_one_level(x, y, z, P.cell[lvl], P.inv[lvl], tb, s0, s1);
  scratch[(size_t)lvl * n + p] = make_float2(s0, s1);   // coalesced 8B/lane
}

// ---------------- Pass 2: transpose scratch [L][N] -> out [N][2L] -----------
__global__ __launch_bounds__(256) void hg_transpose(
    const float2* __restrict__ scratch,
    float* __restrict__ out, int n) {
  __shared__ float s[128][33];                   // +1 pad breaks bank conflicts
  const int p0 = blockIdx.x * 128;
  const int t  = threadIdx.x;

#pragma unroll
  for (int it = 0; it < 8; ++it) {               // 2 levels per iteration
    const int l  = it * 2 + (t >> 7);
    const int pl = t & 127;
    if (p0 + pl < n) {
      const float2 v = scratch[(size_t)l * n + (p0 + pl)];  // coalesced
      s[pl][2 * l + 0] = v.x;
      s[pl][2 * l + 1] = v.y;
    }
  }
  __syncthreads();

#pragma unroll
  for (int i = 0; i < 4; ++i) {                  // 1024 float4 per tile
    const int j   = i * 256 + t;
    const int row = j >> 3;                      // 8 float4 per out row
    const int c4  = j & 7;
    if (p0 + row < n) {
      const float4 v = make_float4(s[row][c4 * 4 + 0], s[row][c4 * 4 + 1],
                                   s[row][c4 * 4 + 2], s[row][c4 * 4 + 3]);
      ((float4*)out)[(size_t)(p0 + row) * 8 + c4] = v;  // full-line 16B/lane
    }
  }
}

// ---------------- Fallback: point-major (only if ws too small) --------------
__global__ __launch_bounds__(256) void hg_encode(
    const float* __restrict__ xyz,
    const float* __restrict__ tables,
    float* __restrict__ out,
    int n, HGParams P) {
  int p = blockIdx.x * 256 + threadIdx.x;
  if (p >= n) return;
  const float x = xyz[3 * (size_t)p + 0];
  const float y = xyz[3 * (size_t)p + 1];
  const float z = xyz[3 * (size_t)p + 2];
  float o[2 * LVLS];
#pragma unroll
  for (int l = 0; l < LVLS; ++l) {
    const float2* __restrict__ tb = (const float2*)tables + (size_t)l * T_SZ;
    float s0, s1;
    encode_one_level(x, y, z, P.cell[l], P.inv[l], tb, s0, s1);
    o[2 * l + 0] = s0;
    o[2 * l + 1] = s1;
  }
  float4* o4 = (float4*)(out + (size_t)p * (2 * LVLS));
#pragma unroll
  for (int i = 0; i < 8; ++i)
    o4[i] = make_float4(o[4 * i + 0], o[4 * i + 1], o[4 * i + 2], o[4 * i + 3]);
}

extern "C" void kernel_launch(void* const* d_in, const int* in_sizes, int n_in,
                              void* d_out, int out_size, void* d_ws, size_t ws_size,
                              hipStream_t stream) {
  const float* xyz    = (const float*)d_in[0];
  const float* tables = (const float*)d_in[1];
  float* out = (float*)d_out;
  const int n = in_sizes[0] / 3;

  // Replicate Python's RES computation bit-for-bit (same glibc libm doubles).
  HGParams P;
  const double B = exp((log(2048.0) - log(16.0)) / 15.0);
  for (int i = 0; i < LVLS; ++i) {
    const int r = (int)floor(16.0 * pow(B, (double)i));
    const double cd = 2.0 / (double)r;
    P.cell[i] = (float)cd;
    P.inv[i]  = 1.0f / P.cell[i];
  }

  const size_t need = (size_t)n * LVLS * sizeof(float2);   // 128 MB at N=1M
  if (ws_size >= need) {
    const int nb = (n + 255) / 256;
    hg_gather<<<dim3(LVLS * nb), 256, 0, stream>>>(
        xyz, tables, (float2*)d_ws, n, nb, P);
    const int tb = (n + 127) / 128;
    hg_transpose<<<tb, 256, 0, stream>>>((const float2*)d_ws, out, n);
  } else {
    hg_encode<<<(n + 255) / 256, 256, 0, stream>>>(xyz, tables, out, n, P);
  }
}

// Round 7
// 638.074 us; speedup vs baseline: 2.0392x; 1.0124x over previous
//
#include <hip/hip_runtime.h>
#include <math.h>

// HashGridEncoder, level-major two-pass.
// Pass 1 (hg_gather): all resident blocks share one level -> 4 MiB table fits
//   each XCD L2. Writes scratch in CHUNK-MAJOR layout [chunk][L][256] float2
//   (2 KB contiguous per block) so pass 2 reads are fully contiguous.
// Pass 2 (hg_transpose): per 256-pt chunk, read contiguous 32 KB, LDS-stage,
//   write full 128B out lines.
// Fallback (hg_encode): point-major single kernel if ws_size too small.

static constexpr unsigned T_SZ  = 524288u;      // 2^19
static constexpr unsigned TMASK = T_SZ - 1u;
static constexpr int      LVLS  = 16;
static constexpr unsigned PI1   = 2654435761u;
static constexpr unsigned PI2   = 805459861u;

struct HGParams {
  float cell[LVLS];   // (float)(2.0 / res)
  float inv[LVLS];    // 1.0f / cell
};

__device__ __forceinline__ void encode_one_level(
    float x, float y, float z, float cell, float inv,
    const float2* __restrict__ tb, float& s0, float& s1) {
  const float fx = floorf((x + 1.0f) * inv);
  const float fy = floorf((y + 1.0f) * inv);
  const float fz = floorf((z + 1.0f) * inv);
  const float dx = (x - (fx * cell - 1.0f)) * inv;
  const float dy = (y - (fy * cell - 1.0f)) * inv;
  const float dz = (z - (fz * cell - 1.0f)) * inv;

  const unsigned hx0 = (unsigned)(int)fx;           // * PI0 = 1
  const unsigned hy0 = (unsigned)(int)fy * PI1;
  const unsigned hz0 = (unsigned)(int)fz * PI2;
  const unsigned hx1 = hx0 + 1u;
  const unsigned hy1 = hy0 + PI1;
  const unsigned hz1 = hz0 + PI2;

  const unsigned i000 = (hx0 ^ hy0 ^ hz0) & TMASK;
  const unsigned i001 = (hx0 ^ hy0 ^ hz1) & TMASK;
  const unsigned i010 = (hx0 ^ hy1 ^ hz0) & TMASK;
  const unsigned i011 = (hx0 ^ hy1 ^ hz1) & TMASK;
  const unsigned i100 = (hx1 ^ hy0 ^ hz0) & TMASK;
  const unsigned i101 = (hx1 ^ hy0 ^ hz1) & TMASK;
  const unsigned i110 = (hx1 ^ hy1 ^ hz0) & TMASK;
  const unsigned i111 = (hx1 ^ hy1 ^ hz1) & TMASK;

  const float2 e000 = tb[i000];
  const float2 e001 = tb[i001];
  const float2 e010 = tb[i010];
  const float2 e011 = tb[i011];
  const float2 e100 = tb[i100];
  const float2 e101 = tb[i101];
  const float2 e110 = tb[i110];
  const float2 e111 = tb[i111];

  const float ax = 1.0f - dx, ay = 1.0f - dy, az = 1.0f - dz;
  const float w00 = ax * ay, w01 = ax * dy, w10 = dx * ay, w11 = dx * dy;
  const float w000 = w00 * az, w001 = w00 * dz;
  const float w010 = w01 * az, w011 = w01 * dz;
  const float w100 = w10 * az, w101 = w10 * dz;
  const float w110 = w11 * az, w111 = w11 * dz;

  s0 = w000 * e000.x;
  s1 = w000 * e000.y;
  s0 = fmaf(w001, e001.x, s0); s1 = fmaf(w001, e001.y, s1);
  s0 = fmaf(w010, e010.x, s0); s1 = fmaf(w010, e010.y, s1);
  s0 = fmaf(w011, e011.x, s0); s1 = fmaf(w011, e011.y, s1);
  s0 = fmaf(w100, e100.x, s0); s1 = fmaf(w100, e100.y, s1);
  s0 = fmaf(w101, e101.x, s0); s1 = fmaf(w101, e101.y, s1);
  s0 = fmaf(w110, e110.x, s0); s1 = fmaf(w110, e110.y, s1);
  s0 = fmaf(w111, e111.x, s0); s1 = fmaf(w111, e111.y, s1);
}

// ---- Pass 1: level-major gather -> scratch [chunk][LVLS][256] float2 -------
__global__ __launch_bounds__(256) void hg_gather(
    const float* __restrict__ xyz,
    const float* __restrict__ tables,
    float2* __restrict__ scratch,
    int n, int nb, HGParams P) {
  const int lvl = blockIdx.x / nb;               // consecutive blocks share a level
  const int c   = blockIdx.x % nb;
  const int p   = c * 256 + threadIdx.x;
  if (p >= n) return;

  const float x = xyz[3 * (size_t)p + 0];
  const float y = xyz[3 * (size_t)p + 1];
  const float z = xyz[3 * (size_t)p + 2];

  const float2* __restrict__ tb = (const float2*)tables + (size_t)lvl * T_SZ;
  float s0, s1;
  encode_one_level(x, y, z, P.cell[lvl], P.inv[lvl], tb, s0, s1);
  // chunk-major: 2 KB contiguous per block write, 32 KB contiguous per chunk
  scratch[((size_t)c * LVLS + lvl) * 256 + threadIdx.x] = make_float2(s0, s1);
}

// ---- Pass 2: chunk transpose [LVLS][256] -> out rows [256][2*LVLS] ---------
__global__ __launch_bounds__(256) void hg_transpose(
    const float4* __restrict__ sc4,
    float4* __restrict__ out4, int n) {
  __shared__ float s[256][33];                   // stride 33: <=2-way (free)
  const int c = blockIdx.x;
  const int t = threadIdx.x;
  const size_t base = (size_t)c * 2048;          // 2048 float4 per chunk

#pragma unroll
  for (int i = 0; i < 8; ++i) {                  // contiguous 32 KB read
    const int q   = i * 256 + t;
    const float4 v = sc4[base + q];
    const int lvl = q >> 7;                      // 128 float4 per level
    const int pp  = (q & 127) * 2;               // 2 points per float4
    s[pp    ][2 * lvl + 0] = v.x;
    s[pp    ][2 * lvl + 1] = v.y;
    s[pp + 1][2 * lvl + 0] = v.z;
    s[pp + 1][2 * lvl + 1] = v.w;
  }
  __syncthreads();

  const int p0 = c * 256;
#pragma unroll
  for (int j = 0; j < 8; ++j) {                  // full 128B out lines
    const int w   = j * 256 + t;
    const int row = w >> 3;
    const int c4  = w & 7;
    if (p0 + row < n)
      out4[(size_t)(p0 + row) * 8 + c4] =
          make_float4(s[row][4 * c4 + 0], s[row][4 * c4 + 1],
                      s[row][4 * c4 + 2], s[row][4 * c4 + 3]);
  }
}

// ---- Fallback: point-major (only if ws too small) --------------------------
__global__ __launch_bounds__(256) void hg_encode(
    const float* __restrict__ xyz,
    const float* __restrict__ tables,
    float* __restrict__ out,
    int n, HGParams P) {
  int p = blockIdx.x * 256 + threadIdx.x;
  if (p >= n) return;
  const float x = xyz[3 * (size_t)p + 0];
  const float y = xyz[3 * (size_t)p + 1];
  const float z = xyz[3 * (size_t)p + 2];
  float o[2 * LVLS];
#pragma unroll
  for (int l = 0; l < LVLS; ++l) {
    const float2* __restrict__ tb = (const float2*)tables + (size_t)l * T_SZ;
    float s0, s1;
    encode_one_level(x, y, z, P.cell[l], P.inv[l], tb, s0, s1);
    o[2 * l + 0] = s0;
    o[2 * l + 1] = s1;
  }
  float4* o4 = (float4*)(out + (size_t)p * (2 * LVLS));
#pragma unroll
  for (int i = 0; i < 8; ++i)
    o4[i] = make_float4(o[4 * i + 0], o[4 * i + 1], o[4 * i + 2], o[4 * i + 3]);
}

extern "C" void kernel_launch(void* const* d_in, const int* in_sizes, int n_in,
                              void* d_out, int out_size, void* d_ws, size_t ws_size,
                              hipStream_t stream) {
  const float* xyz    = (const float*)d_in[0];
  const float* tables = (const float*)d_in[1];
  float* out = (float*)d_out;
  const int n = in_sizes[0] / 3;

  // Replicate Python's RES computation bit-for-bit (same glibc libm doubles).
  HGParams P;
  const double B = exp((log(2048.0) - log(16.0)) / 15.0);
  for (int i = 0; i < LVLS; ++i) {
    const int r = (int)floor(16.0 * pow(B, (double)i));
    const double cd = 2.0 / (double)r;
    P.cell[i] = (float)cd;
    P.inv[i]  = 1.0f / P.cell[i];
  }

  const int nc = (n + 255) / 256;                           // 256-pt chunks
  const size_t need = (size_t)nc * LVLS * 256 * sizeof(float2);
  if (ws_size >= need) {
    hg_gather<<<dim3(LVLS * nc), 256, 0, stream>>>(
        xyz, tables, (float2*)d_ws, n, nc, P);
    hg_transpose<<<nc, 256, 0, stream>>>(
        (const float4*)d_ws, (float4*)out, n);
  } else {
    hg_encode<<<(n + 255) / 256, 256, 0, stream>>>(xyz, tables, out, n, P);
  }
}